// Round 4
// baseline (861.398 us; speedup 1.0000x reference)
//
#include <hip/hip_runtime.h>
#include <cstdint>
#include <cstddef>

// Problem constants
#define BB 4
#define SS 4096
#define DD 256
#define SCORE_SCALE (1.0f/16.0f)   // 1/sqrt(256)
#define PIW 0.5f
#define NROWS (BB * SS)            // 16384 flattened rows

typedef float          f32x4  __attribute__((ext_vector_type(4)));
typedef __bf16         bf16v8 __attribute__((ext_vector_type(8)));
typedef unsigned short u16v8  __attribute__((ext_vector_type(8)));
typedef unsigned short u16v4  __attribute__((ext_vector_type(4)));

__device__ __forceinline__ f32x4 mfma_bf16(u16v8 a, u16v8 b, f32x4 c) {
    return __builtin_amdgcn_mfma_f32_16x16x32_bf16(
        __builtin_bit_cast(bf16v8, a), __builtin_bit_cast(bf16v8, b), c, 0, 0, 0);
}

__device__ __forceinline__ unsigned short f2bf(float f) {
    unsigned u = __float_as_uint(f);
    u += 0x7FFFu + ((u >> 16) & 1u);           // RNE (inputs finite)
    return (unsigned short)(u >> 16);
}
__device__ __forceinline__ float bf2f(unsigned short h) {
    return __uint_as_float(((unsigned)h) << 16);
}
__device__ __forceinline__ unsigned fenc(float x) {
    unsigned u = __float_as_uint(x);
    return (u & 0x80000000u) ? ~u : (u | 0x80000000u);
}
__device__ __forceinline__ float fdec(unsigned e) {
    return __uint_as_float((e & 0x80000000u) ? (e ^ 0x80000000u) : ~e);
}

// ---------------------------------------------------------------------------
// Projections (fp32 vector GEMM, precision-critical): C = A[16384,256]@W[256,256].
// z=0: qh/ql bf16 split. z=1: kh/kl split. z=2: vT bf16 transposed [B][D][S].
// Also inits gmax.
// ---------------------------------------------------------------------------
#define TM 128
#define TN 128
#define TK 16
#define PADW 132

__global__ __launch_bounds__(256) void proj_kernel(
    const float* __restrict__ query, const float* __restrict__ key_, const float* __restrict__ value,
    const float* __restrict__ Wq, const float* __restrict__ Wk, const float* __restrict__ Wv,
    unsigned short* __restrict__ qh, unsigned short* __restrict__ ql,
    unsigned short* __restrict__ kh, unsigned short* __restrict__ kl,
    unsigned short* __restrict__ vT, unsigned* __restrict__ gmax)
{
    const int z = blockIdx.z;
    const float* A = (z == 0) ? query : (z == 1) ? key_ : value;
    const float* W = (z == 0) ? Wq    : (z == 1) ? Wk   : Wv;
    if (z == 0 && blockIdx.x == 0 && blockIdx.y == 0 && threadIdx.x == 0)
        *gmax = 0x007FFFFFu;   // fenc(-inf)

    const int K = DD, N = DD;
    __shared__ float As[TK][PADW];
    __shared__ float Bs[TK][PADW];
    const int tid = threadIdx.x;
    const int tx = tid & 15, ty = tid >> 4;
    const int rowBase = blockIdx.y * TM;   // flattened B*S row
    const int colBase = blockIdx.x * TN;

    float acc[8][8] = {};

    for (int k0 = 0; k0 < K; k0 += TK) {
        #pragma unroll
        for (int i = 0; i < 2; i++) {
            int idx = tid + i * 256;
            int r = idx >> 2, kq = idx & 3;
            const float4 av = *(const float4*)&A[(size_t)(rowBase + r) * K + k0 + kq * 4];
            As[kq * 4 + 0][r] = av.x; As[kq * 4 + 1][r] = av.y;
            As[kq * 4 + 2][r] = av.z; As[kq * 4 + 3][r] = av.w;
        }
        #pragma unroll
        for (int i = 0; i < 2; i++) {
            int idx = tid + i * 256;
            int kk = idx >> 5, cq = idx & 31;
            *(float4*)&Bs[kk][cq * 4] = *(const float4*)&W[(size_t)(k0 + kk) * N + colBase + cq * 4];
        }
        __syncthreads();
        #pragma unroll
        for (int kk = 0; kk < TK; kk++) {
            float a[8], b[8];
            *(float4*)&a[0] = *(const float4*)&As[kk][ty * 8];
            *(float4*)&a[4] = *(const float4*)&As[kk][ty * 8 + 4];
            *(float4*)&b[0] = *(const float4*)&Bs[kk][tx * 8];
            *(float4*)&b[4] = *(const float4*)&Bs[kk][tx * 8 + 4];
            #pragma unroll
            for (int i = 0; i < 8; i++)
                #pragma unroll
                for (int j = 0; j < 8; j++)
                    acc[i][j] = fmaf(a[i], b[j], acc[i][j]);
        }
        __syncthreads();
    }

    #pragma unroll
    for (int i = 0; i < 8; i++) {
        const int gr = rowBase + ty * 8 + i;           // flattened B*S row
        if (z == 2) {
            const int b2 = gr >> 12, s2 = gr & (SS - 1);
            #pragma unroll
            for (int j = 0; j < 8; j++) {
                int col = colBase + tx * 8 + j;
                vT[((size_t)b2 * DD + col) * SS + s2] = f2bf(acc[i][j]);
            }
        } else {
            unsigned short h[8], l[8];
            #pragma unroll
            for (int j = 0; j < 8; j++) {
                h[j] = f2bf(acc[i][j]);
                l[j] = f2bf(acc[i][j] - bf2f(h[j]));
            }
            unsigned short* H = (z == 0) ? qh : kh;
            unsigned short* L = (z == 0) ? ql : kl;
            size_t base = (size_t)gr * DD + colBase + tx * 8;
            *(u16v4*)&H[base]     = (u16v4){h[0], h[1], h[2], h[3]};
            *(u16v4*)&H[base + 4] = (u16v4){h[4], h[5], h[6], h[7]};
            *(u16v4*)&L[base]     = (u16v4){l[0], l[1], l[2], l[3]};
            *(u16v4*)&L[base + 4] = (u16v4){l[4], l[5], l[6], l[7]};
        }
    }
}

// ---------------------------------------------------------------------------
// Scores: C = (q@k^T)/16 via split-bf16 MFMA: qh*kh + qh*kl + ql*kh.
// 128x128 C-tile, 4 waves (2x2 of 64x64), BK=32.
// Epilogue: per-row (max, sumexp) over this 128-col tile -> tmaxg/tsumg,
// plus block max -> gmax. All computed from register-resident acc.
// ---------------------------------------------------------------------------
#define SPAD 40   // 32 + 8 bf16 LDS row stride

__global__ __launch_bounds__(256) void scores_mfma(
    const unsigned short* __restrict__ qh, const unsigned short* __restrict__ ql,
    const unsigned short* __restrict__ kh, const unsigned short* __restrict__ kl,
    float* __restrict__ attn, unsigned* __restrict__ gmax,
    float* __restrict__ tmaxg, float* __restrict__ tsumg)
{
    const int b = blockIdx.z;
    const size_t boff = (size_t)b * SS * DD;
    const unsigned short* Qh = qh + boff;
    const unsigned short* Ql = ql + boff;
    const unsigned short* Kh = kh + boff;
    const unsigned short* Kl = kl + boff;
    float* C = attn + (size_t)b * SS * SS;

    __shared__ unsigned short Ah[128][SPAD];
    __shared__ unsigned short Al[128][SPAD];
    __shared__ unsigned short Bh[128][SPAD];
    __shared__ unsigned short Bl[128][SPAD];
    __shared__ float s_m[4][64];
    __shared__ float s_s[4][64];
    __shared__ float red[128];

    const int tid = threadIdx.x;
    const int lane = tid & 63, w = tid >> 6;
    const int wr = (w >> 1) * 64, wc = (w & 1) * 64;
    const int m = lane & 15, qq = lane >> 4;
    const int rowBase = blockIdx.y * 128;
    const int colBase = blockIdx.x * 128;

    f32x4 acc[4][4];
    #pragma unroll
    for (int i = 0; i < 4; i++)
        #pragma unroll
        for (int j = 0; j < 4; j++)
            acc[i][j] = (f32x4){0.f, 0.f, 0.f, 0.f};

    const int chunk = (tid & 3) * 8;        // bf16 offset within 32-wide k-slab
    const int srow  = tid >> 2;             // 0..63

    for (int k0 = 0; k0 < DD; k0 += 32) {
        #pragma unroll
        for (int i = 0; i < 2; i++) {
            int r = srow + i * 64;
            size_t ga = (size_t)(rowBase + r) * DD + k0 + chunk;
            size_t gb = (size_t)(colBase + r) * DD + k0 + chunk;
            *(u16v8*)&Ah[r][chunk] = *(const u16v8*)&Qh[ga];
            *(u16v8*)&Al[r][chunk] = *(const u16v8*)&Ql[ga];
            *(u16v8*)&Bh[r][chunk] = *(const u16v8*)&Kh[gb];
            *(u16v8*)&Bl[r][chunk] = *(const u16v8*)&Kl[gb];
        }
        __syncthreads();

        const int kb = qq * 8;
        u16v8 ah[4], al[4], bh[4], bl[4];
        #pragma unroll
        for (int i = 0; i < 4; i++) {
            ah[i] = *(const u16v8*)&Ah[wr + i * 16 + m][kb];
            al[i] = *(const u16v8*)&Al[wr + i * 16 + m][kb];
            bh[i] = *(const u16v8*)&Bh[wc + i * 16 + m][kb];
            bl[i] = *(const u16v8*)&Bl[wc + i * 16 + m][kb];
        }
        #pragma unroll
        for (int i = 0; i < 4; i++)
            #pragma unroll
            for (int j = 0; j < 4; j++) {
                acc[i][j] = mfma_bf16(ah[i], bh[j], acc[i][j]);
                acc[i][j] = mfma_bf16(ah[i], bl[j], acc[i][j]);
                acc[i][j] = mfma_bf16(al[i], bh[j], acc[i][j]);
            }
        __syncthreads();
    }

    // scale once; all consumers (C store, stats, gmax) use scaled values
    #pragma unroll
    for (int i = 0; i < 4; i++)
        #pragma unroll
        for (int j = 0; j < 4; j++)
            acc[i][j] *= SCORE_SCALE;

    // store raw scores (nontemporal: pure stream)
    #pragma unroll
    for (int i = 0; i < 4; i++)
        #pragma unroll
        for (int j = 0; j < 4; j++)
            #pragma unroll
            for (int r = 0; r < 4; r++) {
                int row = rowBase + wr + i * 16 + qq * 4 + r;
                int col = colBase + wc + j * 16 + m;
                __builtin_nontemporal_store(acc[i][j][r], &C[(size_t)row * SS + col]);
            }

    // ---- per-row tile stats (flash-style), register resident ----
    float lmax[16];
    #pragma unroll
    for (int i = 0; i < 4; i++)
        #pragma unroll
        for (int r = 0; r < 4; r++)
            lmax[i * 4 + r] = fmaxf(fmaxf(acc[i][0][r], acc[i][1][r]),
                                    fmaxf(acc[i][2][r], acc[i][3][r]));
    #pragma unroll
    for (int t = 0; t < 16; t++) {
        #pragma unroll
        for (int msk = 1; msk < 16; msk <<= 1)
            lmax[t] = fmaxf(lmax[t], __shfl_xor(lmax[t], msk));
    }
    if (m == 0) {
        #pragma unroll
        for (int i = 0; i < 4; i++)
            #pragma unroll
            for (int r = 0; r < 4; r++)
                s_m[w][i * 16 + qq * 4 + r] = lmax[i * 4 + r];
    }
    __syncthreads();
    float lsum[16];
    #pragma unroll
    for (int i = 0; i < 4; i++)
        #pragma unroll
        for (int r = 0; r < 4; r++) {
            int idx = i * 16 + qq * 4 + r;
            float rm = fmaxf(s_m[w][idx], s_m[w ^ 1][idx]);
            float s = 0.f;
            #pragma unroll
            for (int j = 0; j < 4; j++)
                s += __expf(acc[i][j][r] - rm);
            lsum[i * 4 + r] = s;
        }
    #pragma unroll
    for (int t = 0; t < 16; t++) {
        #pragma unroll
        for (int msk = 1; msk < 16; msk <<= 1)
            lsum[t] += __shfl_xor(lsum[t], msk);
    }
    if (m == 0) {
        #pragma unroll
        for (int i = 0; i < 4; i++)
            #pragma unroll
            for (int r = 0; r < 4; r++)
                s_s[w][i * 16 + qq * 4 + r] = lsum[i * 4 + r];
    }
    __syncthreads();

    if (tid < 128) {
        int wp = tid >> 6, lr = tid & 63;
        float tm = fmaxf(s_m[2 * wp][lr], s_m[2 * wp + 1][lr]);
        float ts = s_s[2 * wp][lr] + s_s[2 * wp + 1][lr];   // same reference max
        size_t gi = (size_t)blockIdx.x * NROWS + (size_t)b * SS + rowBase + tid;
        tmaxg[gi] = tm;
        tsumg[gi] = ts;
        red[tid] = tm;
    }
    __syncthreads();
    for (int s2 = 64; s2 > 0; s2 >>= 1) {
        if (tid < s2) red[tid] = fmaxf(red[tid], red[tid + s2]);
        __syncthreads();
    }
    if (tid == 0) atomicMax(gmax, fenc(red[0]));
}

// ---------------------------------------------------------------------------
// Merge per-tile stats into per-row (max, 1/sum), folding in the diag bias
// (needs final gmax). Reads 4 MB stats + 16K diag elements. Tiny.
// ---------------------------------------------------------------------------
__global__ __launch_bounds__(256) void stats_merge(
    const float* __restrict__ tmaxg, const float* __restrict__ tsumg,
    const float* __restrict__ attn, const unsigned* __restrict__ gmax,
    float* __restrict__ rowm, float* __restrict__ rowinv)
{
    const int grow = blockIdx.x * 256 + threadIdx.x;   // 0..16383
    const int b = grow >> 12, i = grow & (SS - 1);
    const float bias = PIW * fdec(*gmax);

    float tm[32];
    float mx = -INFINITY;
    #pragma unroll
    for (int t = 0; t < 32; t++) {
        tm[t] = tmaxg[(size_t)t * NROWS + grow];
        mx = fmaxf(mx, tm[t]);
    }
    const float dii = attn[(size_t)b * SS * SS + (size_t)i * SS + i];
    mx = fmaxf(mx, dii + bias);

    float s = 0.f;
    #pragma unroll
    for (int t = 0; t < 32; t++)
        s += tsumg[(size_t)t * NROWS + grow] * __expf(tm[t] - mx);
    // replace unbiased diag contribution with biased one
    s += __expf(dii + bias - mx) - __expf(dii - mx);

    rowm[grow] = mx;
    rowinv[grow] = 1.0f / s;
}

// ---------------------------------------------------------------------------
// Fused softmax + AV, barrier-free ownership layout.
// Wave = 16 output rows x 256 cols, K split in half across a wave pair
// (u=0: k 0..2047, u=1: k 2048..4095). Lane (m,qq) owns raw-score elements
// A[row m][k = 32c+qq*8..+8] - it loads them (nt, prefetched one 128-step
// ahead), exps them (diag bias folded), writes fp32 weights back (nt), and
// feeds them directly to MFMA as its own A-fragment. vT B-fragments are
// per-lane L2 reads (batch pinned to an XCD pair). No LDS/barriers in the
// loop; one end-of-kernel LDS exchange sums the two K-half accumulators.
// Grid 512 x 256 thr = 2048 waves = one full generation at 8 waves/CU.
// ---------------------------------------------------------------------------
#define AV_LOADA(pf, lk)                                                      \
    _Pragma("unroll")                                                         \
    for (int v_ = 0; v_ < 4; v_++) {                                          \
        pf[2*v_]   = __builtin_nontemporal_load(                              \
            (const f32x4*)&Arow[(lk) + v_*32 + qq*8]);                        \
        pf[2*v_+1] = __builtin_nontemporal_load(                              \
            (const f32x4*)&Arow[(lk) + v_*32 + qq*8 + 4]);                    \
    }

#define AV_KK(pf, kkk, lk)                                                    \
    {                                                                         \
        const int cb_ = (lk) + (kkk)*32 + qq*8;                               \
        _Pragma("unroll")                                                     \
        for (int n_ = 0; n_ < 16; n_++)                                       \
            bf[n_] = *(const u16v8*)&Bp[n_][cb_];                             \
        f32x4 lo_ = pf[2*(kkk)], hi_ = pf[2*(kkk)+1];                         \
        float wv_[8];                                                         \
        _Pragma("unroll")                                                     \
        for (int e_ = 0; e_ < 8; e_++) {                                      \
            float x_ = (e_ < 4) ? lo_[e_ & 3] : hi_[e_ & 3];                  \
            x_ += ((cg0 + cb_ + e_) == rr) ? bias : 0.0f;                     \
            wv_[e_] = __expf(x_ - mr) * ri;                                   \
        }                                                                     \
        __builtin_nontemporal_store((f32x4){wv_[0], wv_[1], wv_[2], wv_[3]},  \
                                    (f32x4*)&Arow[cb_]);                      \
        __builtin_nontemporal_store((f32x4){wv_[4], wv_[5], wv_[6], wv_[7]},  \
                                    (f32x4*)&Arow[cb_ + 4]);                  \
        u16v8 af_ = (u16v8){f2bf(wv_[0]), f2bf(wv_[1]), f2bf(wv_[2]),         \
                            f2bf(wv_[3]), f2bf(wv_[4]), f2bf(wv_[5]),         \
                            f2bf(wv_[6]), f2bf(wv_[7])};                      \
        _Pragma("unroll")                                                     \
        for (int n_ = 0; n_ < 16; n_++)                                       \
            acc[n_] = mfma_bf16(af_, bf[n_], acc[n_]);                        \
    }

__global__ __launch_bounds__(256) void av_softmax_mfma(
    float* __restrict__ attn, const unsigned short* __restrict__ vT,
    const float* __restrict__ rowm, const float* __restrict__ rowinv,
    const unsigned* __restrict__ gmax, float* __restrict__ out)
{
    // XCD-aware decode: block i -> XCD i%8; batch b owns XCDs {2b, 2b+1}
    // so vT[b] (2 MB) stays L2-resident there.
    const int lin = blockIdx.x;
    const int b = (lin & 7) >> 1;
    const int rowTile = ((lin >> 3) << 1) | (lin & 1);   // 0..127
    const int rowBase = rowTile * 32;

    float* A = attn + (size_t)b * SS * SS;
    const unsigned short* Bv = vT + (size_t)b * DD * SS;   // [256][4096]
    const float bias = PIW * fdec(*gmax);

    __shared__ float redl[2][64][64];   // 32 KB end-of-kernel exchange

    const int tid = threadIdx.x;
    const int lane = tid & 63, w = tid >> 6;
    const int pair = w >> 1;            // 16-row group within the block
    const int u = w & 1;                // K half
    const int m = lane & 15, qq = lane >> 4;

    const int rr = rowBase + pair * 16 + m;     // my owned A row
    const int cg0 = u * 2048;                   // global col base of my K half
    float* Arow = A + (size_t)rr * SS + cg0;
    const float mr = rowm[b * SS + rr];
    const float ri = rowinv[b * SS + rr];

    const unsigned short* Bp[16];
    #pragma unroll
    for (int n = 0; n < 16; n++)
        Bp[n] = Bv + (size_t)(n * 16 + m) * SS + cg0;

    f32x4 acc[16];
    #pragma unroll
    for (int n = 0; n < 16; n++)
        acc[n] = (f32x4){0.f, 0.f, 0.f, 0.f};

    f32x4 pfA[8], pfB[8];
    u16v8 bf[16];

    AV_LOADA(pfA, 0)

    #pragma unroll 1
    for (int t = 0; t < 16; t += 2) {
        const int lk = t * 128;
        AV_LOADA(pfB, lk + 128)
        AV_KK(pfA, 0, lk)
        AV_KK(pfA, 1, lk)
        AV_KK(pfA, 2, lk)
        AV_KK(pfA, 3, lk)
        if (t + 2 < 16) {
            AV_LOADA(pfA, lk + 256)
        }
        AV_KK(pfB, 0, lk + 128)
        AV_KK(pfB, 1, lk + 128)
        AV_KK(pfB, 2, lk + 128)
        AV_KK(pfB, 3, lk + 128)
    }

    // sum the two K-half partials, then store
    if (u == 1) {
        #pragma unroll
        for (int n = 0; n < 16; n++)
            *(f32x4*)&redl[pair][lane][n * 4] = acc[n];
    }
    __syncthreads();
    if (u == 0) {
        #pragma unroll
        for (int n = 0; n < 16; n++) {
            f32x4 o = acc[n] + *(const f32x4*)&redl[pair][lane][n * 4];
            #pragma unroll
            for (int r = 0; r < 4; r++) {
                int row = rowBase + pair * 16 + qq * 4 + r;
                int col = n * 16 + m;
                __builtin_nontemporal_store(
                    o[r], &out[((size_t)b * SS + row) * DD + col]);
            }
        }
    }
}

extern "C" void kernel_launch(void* const* d_in, const int* in_sizes, int n_in,
                              void* d_out, int out_size, void* d_ws, size_t ws_size,
                              hipStream_t stream)
{
    const float* query = (const float*)d_in[0];
    const float* key_  = (const float*)d_in[1];
    const float* value = (const float*)d_in[2];
    const float* Wq    = (const float*)d_in[3];
    const float* Wk    = (const float*)d_in[4];
    const float* Wv    = (const float*)d_in[5];

    float* out  = (float*)d_out;                          // [B,S,D]
    float* attn = out + (size_t)BB * SS * DD;             // [B,S,S]

    const size_t E = (size_t)BB * SS * DD;                // 4.19M elements
    unsigned short* qh = (unsigned short*)d_ws;
    unsigned short* ql = qh + E;
    unsigned short* kh = ql + E;
    unsigned short* kl = kh + E;
    unsigned short* vT = kl + E;
    float* tmaxg  = (float*)(vT + E);                     // [32][16384]
    float* tsumg  = tmaxg + 32 * (size_t)NROWS;           // [32][16384]
    float* rowm   = tsumg + 32 * (size_t)NROWS;           // [16384]
    float* rowinv = rowm + NROWS;                         // [16384]
    unsigned* gmax = (unsigned*)(rowinv + NROWS);

    // 1) projections: bf16 splits for q,k; transposed bf16 v; gmax init
    proj_kernel<<<dim3(DD / TN, (BB * SS) / TM, 3), 256, 0, stream>>>(
        query, key_, value, Wq, Wk, Wv, qh, ql, kh, kl, vT, gmax);
    // 2) raw scores via split-bf16 MFMA + per-row tile stats + global max
    scores_mfma<<<dim3(SS / 128, SS / 128, BB), 256, 0, stream>>>(
        qh, ql, kh, kl, attn, gmax, tmaxg, tsumg);
    // 3) merge tile stats -> per-row (max, 1/sum) with diag bias
    stats_merge<<<dim3(NROWS / 256), 256, 0, stream>>>(
        tmaxg, tsumg, attn, gmax, rowm, rowinv);
    // 4) fused softmax-normalize (writes fp32 attn output) + attn @ v
    av_softmax_mfma<<<dim3(512), 256, 0, stream>>>(
        attn, vT, rowm, rowinv, gmax, out);
}

// Round 5
// 769.566 us; speedup vs baseline: 1.1193x; 1.1193x over previous
//
#include <hip/hip_runtime.h>
#include <cstdint>
#include <cstddef>

// Problem constants
#define BB 4
#define SS 4096
#define DD 256
#define SCORE_SCALE (1.0f/16.0f)   // 1/sqrt(256)
#define PIW 0.5f
#define NROWS (BB * SS)            // 16384 flattened rows

typedef float          f32x4  __attribute__((ext_vector_type(4)));
typedef __bf16         bf16v8 __attribute__((ext_vector_type(8)));
typedef unsigned short u16v8  __attribute__((ext_vector_type(8)));
typedef unsigned short u16v4  __attribute__((ext_vector_type(4)));

__device__ __forceinline__ f32x4 mfma_bf16(u16v8 a, u16v8 b, f32x4 c) {
    return __builtin_amdgcn_mfma_f32_16x16x32_bf16(
        __builtin_bit_cast(bf16v8, a), __builtin_bit_cast(bf16v8, b), c, 0, 0, 0);
}

__device__ __forceinline__ unsigned short f2bf(float f) {
    unsigned u = __float_as_uint(f);
    u += 0x7FFFu + ((u >> 16) & 1u);           // RNE (inputs finite)
    return (unsigned short)(u >> 16);
}
__device__ __forceinline__ float bf2f(unsigned short h) {
    return __uint_as_float(((unsigned)h) << 16);
}
__device__ __forceinline__ unsigned fenc(float x) {
    unsigned u = __float_as_uint(x);
    return (u & 0x80000000u) ? ~u : (u | 0x80000000u);
}
__device__ __forceinline__ float fdec(unsigned e) {
    return __uint_as_float((e & 0x80000000u) ? (e ^ 0x80000000u) : ~e);
}

// ---------------------------------------------------------------------------
// Projections via split-bf16 MFMA (Ah*Wh + Ah*Wl + Al*Wh ~ fp32 precision):
// C = A[16384,256] @ W[256,256]. 128x128 tile, 4 waves (2x2 of 64x64), BK=32.
// z=0: qh/ql bf16 split. z=1: kh/kl split. z=2: vT bf16 transposed [B][D][S].
// Also inits gmax.
// ---------------------------------------------------------------------------
#define PSPAD 42   // 32 + 10 u16 row stride (W-transpose staging conflicts)

__global__ __launch_bounds__(256) void proj_kernel(
    const float* __restrict__ query, const float* __restrict__ key_, const float* __restrict__ value,
    const float* __restrict__ Wq, const float* __restrict__ Wk, const float* __restrict__ Wv,
    unsigned short* __restrict__ qh, unsigned short* __restrict__ ql,
    unsigned short* __restrict__ kh, unsigned short* __restrict__ kl,
    unsigned short* __restrict__ vT, unsigned* __restrict__ gmax)
{
    const int z = blockIdx.z;
    const float* A = (z == 0) ? query : (z == 1) ? key_ : value;
    const float* W = (z == 0) ? Wq    : (z == 1) ? Wk   : Wv;
    if (z == 0 && blockIdx.x == 0 && blockIdx.y == 0 && threadIdx.x == 0)
        *gmax = 0x007FFFFFu;   // fenc(-inf)

    __shared__ unsigned short Ah[128][PSPAD];
    __shared__ unsigned short Al[128][PSPAD];
    __shared__ unsigned short Bh[128][PSPAD];   // W^T split: [n][k]
    __shared__ unsigned short Bl[128][PSPAD];

    const int tid = threadIdx.x;
    const int lane = tid & 63, w = tid >> 6;
    const int wr = (w >> 1) * 64, wc = (w & 1) * 64;
    const int m = lane & 15, qq = lane >> 4;
    const int rowBase = blockIdx.y * 128;   // flattened B*S row
    const int colBase = blockIdx.x * 128;

    f32x4 acc[4][4];
    #pragma unroll
    for (int i = 0; i < 4; i++)
        #pragma unroll
        for (int j = 0; j < 4; j++)
            acc[i][j] = (f32x4){0.f, 0.f, 0.f, 0.f};

    const int chunk = (tid & 3) * 8;   // float offset within 32-wide k-slab
    const int srow  = tid >> 2;        // 0..63

    for (int k0 = 0; k0 < DD; k0 += 32) {
        // A staging: rows srow, srow+64; 8 fp32 -> bf16 h/l
        #pragma unroll
        for (int i = 0; i < 2; i++) {
            int r = srow + i * 64;
            const float* src = &A[(size_t)(rowBase + r) * DD + k0 + chunk];
            float4 f0 = *(const float4*)src;
            float4 f1 = *(const float4*)(src + 4);
            float v[8] = {f0.x, f0.y, f0.z, f0.w, f1.x, f1.y, f1.z, f1.w};
            u16v8 h, l;
            #pragma unroll
            for (int e = 0; e < 8; e++) {
                h[e] = f2bf(v[e]);
                l[e] = f2bf(v[e] - bf2f(h[e]));
            }
            *(u16v8*)&Ah[r][chunk] = h;
            *(u16v8*)&Al[r][chunk] = l;
        }
        // W staging transposed: W[k0+kk][colBase+n] -> Bh/Bl[n][kk]
        #pragma unroll
        for (int i = 0; i < 4; i++) {
            int idx = tid + i * 256;
            int kk = idx >> 5, nq = idx & 31;
            float4 f = *(const float4*)&W[(size_t)(k0 + kk) * DD + colBase + nq * 4];
            float v[4] = {f.x, f.y, f.z, f.w};
            #pragma unroll
            for (int e = 0; e < 4; e++) {
                unsigned short h = f2bf(v[e]);
                unsigned short l = f2bf(v[e] - bf2f(h));
                Bh[nq * 4 + e][kk] = h;
                Bl[nq * 4 + e][kk] = l;
            }
        }
        __syncthreads();

        const int kb = qq * 8;
        u16v8 ah[4], al[4], bh[4], bl[4];
        #pragma unroll
        for (int i = 0; i < 4; i++) {
            ah[i] = *(const u16v8*)&Ah[wr + i * 16 + m][kb];
            al[i] = *(const u16v8*)&Al[wr + i * 16 + m][kb];
            bh[i] = *(const u16v8*)&Bh[wc + i * 16 + m][kb];
            bl[i] = *(const u16v8*)&Bl[wc + i * 16 + m][kb];
        }
        #pragma unroll
        for (int i = 0; i < 4; i++)
            #pragma unroll
            for (int j = 0; j < 4; j++) {
                acc[i][j] = mfma_bf16(ah[i], bh[j], acc[i][j]);
                acc[i][j] = mfma_bf16(ah[i], bl[j], acc[i][j]);
                acc[i][j] = mfma_bf16(al[i], bh[j], acc[i][j]);
            }
        __syncthreads();
    }

    // epilogue: lane (m,qq) holds C[rowBase+wr+i*16+qq*4+r][colBase+wc+j*16+m]
    #pragma unroll
    for (int i = 0; i < 4; i++) {
        #pragma unroll
        for (int j = 0; j < 4; j++) {
            #pragma unroll
            for (int r = 0; r < 4; r++) {
                const int gr  = rowBase + wr + i * 16 + qq * 4 + r;
                const int col = colBase + wc + j * 16 + m;
                const float v = acc[i][j][r];
                if (z == 2) {
                    const int b2 = gr >> 12, s2 = gr & (SS - 1);
                    vT[((size_t)b2 * DD + col) * SS + s2] = f2bf(v);
                } else {
                    unsigned short h = f2bf(v);
                    unsigned short l = f2bf(v - bf2f(h));
                    unsigned short* H = (z == 0) ? qh : kh;
                    unsigned short* L = (z == 0) ? ql : kl;
                    H[(size_t)gr * DD + col] = h;
                    L[(size_t)gr * DD + col] = l;
                }
            }
        }
    }
}

// ---------------------------------------------------------------------------
// Scores: C = (q@k^T)/16 via split-bf16 MFMA: qh*kh + qh*kl + ql*kh.
// 128x128 C-tile, 4 waves (2x2 of 64x64), BK=32.
// Epilogue: per-row (max, sumexp) over this 128-col tile -> tmaxg/tsumg,
// plus block max -> gmax. All computed from register-resident acc.
// ---------------------------------------------------------------------------
#define SPAD 40   // 32 + 8 bf16 LDS row stride

__global__ __launch_bounds__(256) void scores_mfma(
    const unsigned short* __restrict__ qh, const unsigned short* __restrict__ ql,
    const unsigned short* __restrict__ kh, const unsigned short* __restrict__ kl,
    float* __restrict__ attn, unsigned* __restrict__ gmax,
    float* __restrict__ tmaxg, float* __restrict__ tsumg)
{
    const int b = blockIdx.z;
    const size_t boff = (size_t)b * SS * DD;
    const unsigned short* Qh = qh + boff;
    const unsigned short* Ql = ql + boff;
    const unsigned short* Kh = kh + boff;
    const unsigned short* Kl = kl + boff;
    float* C = attn + (size_t)b * SS * SS;

    __shared__ unsigned short Ah[128][SPAD];
    __shared__ unsigned short Al[128][SPAD];
    __shared__ unsigned short Bh[128][SPAD];
    __shared__ unsigned short Bl[128][SPAD];
    __shared__ float s_m[4][64];
    __shared__ float s_s[4][64];
    __shared__ float red[128];

    const int tid = threadIdx.x;
    const int lane = tid & 63, w = tid >> 6;
    const int wr = (w >> 1) * 64, wc = (w & 1) * 64;
    const int m = lane & 15, qq = lane >> 4;
    const int rowBase = blockIdx.y * 128;
    const int colBase = blockIdx.x * 128;

    f32x4 acc[4][4];
    #pragma unroll
    for (int i = 0; i < 4; i++)
        #pragma unroll
        for (int j = 0; j < 4; j++)
            acc[i][j] = (f32x4){0.f, 0.f, 0.f, 0.f};

    const int chunk = (tid & 3) * 8;        // bf16 offset within 32-wide k-slab
    const int srow  = tid >> 2;             // 0..63

    for (int k0 = 0; k0 < DD; k0 += 32) {
        #pragma unroll
        for (int i = 0; i < 2; i++) {
            int r = srow + i * 64;
            size_t ga = (size_t)(rowBase + r) * DD + k0 + chunk;
            size_t gb = (size_t)(colBase + r) * DD + k0 + chunk;
            *(u16v8*)&Ah[r][chunk] = *(const u16v8*)&Qh[ga];
            *(u16v8*)&Al[r][chunk] = *(const u16v8*)&Ql[ga];
            *(u16v8*)&Bh[r][chunk] = *(const u16v8*)&Kh[gb];
            *(u16v8*)&Bl[r][chunk] = *(const u16v8*)&Kl[gb];
        }
        __syncthreads();

        const int kb = qq * 8;
        u16v8 ah[4], al[4], bh[4], bl[4];
        #pragma unroll
        for (int i = 0; i < 4; i++) {
            ah[i] = *(const u16v8*)&Ah[wr + i * 16 + m][kb];
            al[i] = *(const u16v8*)&Al[wr + i * 16 + m][kb];
            bh[i] = *(const u16v8*)&Bh[wc + i * 16 + m][kb];
            bl[i] = *(const u16v8*)&Bl[wc + i * 16 + m][kb];
        }
        #pragma unroll
        for (int i = 0; i < 4; i++)
            #pragma unroll
            for (int j = 0; j < 4; j++) {
                acc[i][j] = mfma_bf16(ah[i], bh[j], acc[i][j]);
                acc[i][j] = mfma_bf16(ah[i], bl[j], acc[i][j]);
                acc[i][j] = mfma_bf16(al[i], bh[j], acc[i][j]);
            }
        __syncthreads();
    }

    // scale once; all consumers (C store, stats, gmax) use scaled values
    #pragma unroll
    for (int i = 0; i < 4; i++)
        #pragma unroll
        for (int j = 0; j < 4; j++)
            acc[i][j] *= SCORE_SCALE;

    // store raw scores (nontemporal: pure stream)
    #pragma unroll
    for (int i = 0; i < 4; i++)
        #pragma unroll
        for (int j = 0; j < 4; j++)
            #pragma unroll
            for (int r = 0; r < 4; r++) {
                int row = rowBase + wr + i * 16 + qq * 4 + r;
                int col = colBase + wc + j * 16 + m;
                __builtin_nontemporal_store(acc[i][j][r], &C[(size_t)row * SS + col]);
            }

    // ---- per-row tile stats (flash-style), register resident ----
    float lmax[16];
    #pragma unroll
    for (int i = 0; i < 4; i++)
        #pragma unroll
        for (int r = 0; r < 4; r++)
            lmax[i * 4 + r] = fmaxf(fmaxf(acc[i][0][r], acc[i][1][r]),
                                    fmaxf(acc[i][2][r], acc[i][3][r]));
    #pragma unroll
    for (int t = 0; t < 16; t++) {
        #pragma unroll
        for (int msk = 1; msk < 16; msk <<= 1)
            lmax[t] = fmaxf(lmax[t], __shfl_xor(lmax[t], msk));
    }
    if (m == 0) {
        #pragma unroll
        for (int i = 0; i < 4; i++)
            #pragma unroll
            for (int r = 0; r < 4; r++)
                s_m[w][i * 16 + qq * 4 + r] = lmax[i * 4 + r];
    }
    __syncthreads();
    float lsum[16];
    #pragma unroll
    for (int i = 0; i < 4; i++)
        #pragma unroll
        for (int r = 0; r < 4; r++) {
            int idx = i * 16 + qq * 4 + r;
            float rm = fmaxf(s_m[w][idx], s_m[w ^ 1][idx]);
            float s = 0.f;
            #pragma unroll
            for (int j = 0; j < 4; j++)
                s += __expf(acc[i][j][r] - rm);
            lsum[i * 4 + r] = s;
        }
    #pragma unroll
    for (int t = 0; t < 16; t++) {
        #pragma unroll
        for (int msk = 1; msk < 16; msk <<= 1)
            lsum[t] += __shfl_xor(lsum[t], msk);
    }
    if (m == 0) {
        #pragma unroll
        for (int i = 0; i < 4; i++)
            #pragma unroll
            for (int r = 0; r < 4; r++)
                s_s[w][i * 16 + qq * 4 + r] = lsum[i * 4 + r];
    }
    __syncthreads();

    if (tid < 128) {
        int wp = tid >> 6, lr = tid & 63;
        float tm = fmaxf(s_m[2 * wp][lr], s_m[2 * wp + 1][lr]);
        float ts = s_s[2 * wp][lr] + s_s[2 * wp + 1][lr];   // same reference max
        size_t gi = (size_t)blockIdx.x * NROWS + (size_t)b * SS + rowBase + tid;
        tmaxg[gi] = tm;
        tsumg[gi] = ts;
        red[tid] = tm;
    }
    __syncthreads();
    for (int s2 = 64; s2 > 0; s2 >>= 1) {
        if (tid < s2) red[tid] = fmaxf(red[tid], red[tid + s2]);
        __syncthreads();
    }
    if (tid == 0) atomicMax(gmax, fenc(red[0]));
}

// ---------------------------------------------------------------------------
// Merge per-tile stats into per-row (max, 1/sum), folding in the diag bias
// (needs final gmax). Reads 4 MB stats + 16K diag elements. Tiny.
// ---------------------------------------------------------------------------
__global__ __launch_bounds__(256) void stats_merge(
    const float* __restrict__ tmaxg, const float* __restrict__ tsumg,
    const float* __restrict__ attn, const unsigned* __restrict__ gmax,
    float* __restrict__ rowm, float* __restrict__ rowinv)
{
    const int grow = blockIdx.x * 256 + threadIdx.x;   // 0..16383
    const int b = grow >> 12, i = grow & (SS - 1);
    const float bias = PIW * fdec(*gmax);

    float tm[32];
    float mx = -INFINITY;
    #pragma unroll
    for (int t = 0; t < 32; t++) {
        tm[t] = tmaxg[(size_t)t * NROWS + grow];
        mx = fmaxf(mx, tm[t]);
    }
    const float dii = attn[(size_t)b * SS * SS + (size_t)i * SS + i];
    mx = fmaxf(mx, dii + bias);

    float s = 0.f;
    #pragma unroll
    for (int t = 0; t < 32; t++)
        s += tsumg[(size_t)t * NROWS + grow] * __expf(tm[t] - mx);
    // replace unbiased diag contribution with biased one
    s += __expf(dii + bias - mx) - __expf(dii - mx);

    rowm[grow] = mx;
    rowinv[grow] = 1.0f / s;
}

// ---------------------------------------------------------------------------
// Fused softmax + AV. BM=16, BN=256, BK=128. Grid 1024 (4 blocks/CU) with
// XCD-aware decode (batch pinned to an XCD pair -> vT L2-resident).
// A (raw scores) register-prefetched TWO K-steps ahead (2 slots); exp'd once
// (diag bias folded), fp32 weights written back (nt), bf16 staged into a
// small double-buffered LDS tile. B fragments read per-lane from L2.
// One __syncthreads per 128-wide K step.
// ---------------------------------------------------------------------------
__global__ __launch_bounds__(256) void av_softmax_mfma(
    float* __restrict__ attn, const unsigned short* __restrict__ vT,
    const float* __restrict__ rowm, const float* __restrict__ rowinv,
    const unsigned* __restrict__ gmax, float* __restrict__ out)
{
    // block i -> XCD i%8; batch b owns XCDs {2b, 2b+1}
    const int lin = blockIdx.x;
    const int b = (lin & 7) >> 1;
    const int rowTile = ((lin >> 3) << 1) | (lin & 1);   // 0..255
    const int rowBase = rowTile * 16;

    float* A = attn + (size_t)b * SS * SS;
    const unsigned short* Bv = vT + (size_t)b * DD * SS;   // [256][4096]
    const float bias = PIW * fdec(*gmax);

    __shared__ unsigned short As[2][16][136];   // bf16 A tile, dbuf, +8 pad

    const int tid = threadIdx.x;
    const int lane = tid & 63, w = tid >> 6;
    const int m = lane & 15, qq = lane >> 4;

    // A-staging map: thread owns row ra, fp32 cols ch*4 + {0,64}
    const int ra = tid >> 4;              // 0..15
    const int ch = tid & 15;              // float4 chunk
    const int rr = rowBase + ra;
    float* Arow = A + (size_t)rr * SS;
    const float mr = rowm[b * SS + rr];
    const float ri = rowinv[b * SS + rr];

    // per-lane vT row bases (constant over k)
    const unsigned short* Bp[4];
    #pragma unroll
    for (int j = 0; j < 4; j++)
        Bp[j] = Bv + (size_t)(w * 64 + j * 16 + m) * SS;

    f32x4 acc[4];
    #pragma unroll
    for (int j = 0; j < 4; j++)
        acc[j] = (f32x4){0.f, 0.f, 0.f, 0.f};

    f32x4 pfs[2][2];   // 2 prefetch slots x 2 float4 per thread

    auto loadA = [&](int kbase, int slot) {
        #pragma unroll
        for (int u = 0; u < 2; u++)
            pfs[slot][u] = __builtin_nontemporal_load(
                (const f32x4*)&Arow[kbase + ch * 4 + u * 64]);
    };
    // exp-normalize slot, write fp32 weights back, stage bf16 into As[buf]
    auto procStore = [&](int kbase, int slot, int buf) {
        #pragma unroll
        for (int u = 0; u < 2; u++) {
            int c = ch * 4 + u * 64;
            int j0 = kbase + c;
            float e0 = pfs[slot][u][0] + ((j0 + 0 == rr) ? bias : 0.0f);
            float e1 = pfs[slot][u][1] + ((j0 + 1 == rr) ? bias : 0.0f);
            float e2 = pfs[slot][u][2] + ((j0 + 2 == rr) ? bias : 0.0f);
            float e3 = pfs[slot][u][3] + ((j0 + 3 == rr) ? bias : 0.0f);
            float w0 = __expf(e0 - mr) * ri;
            float w1 = __expf(e1 - mr) * ri;
            float w2 = __expf(e2 - mr) * ri;
            float w3 = __expf(e3 - mr) * ri;
            f32x4 wv = (f32x4){w0, w1, w2, w3};
            __builtin_nontemporal_store(wv, (f32x4*)&Arow[j0]);
            *(u16v4*)&As[buf][ra][c] =
                (u16v4){f2bf(w0), f2bf(w1), f2bf(w2), f2bf(w3)};
        }
    };

    const int NT = SS / 128;   // 32 K-steps

    // prologue: buf0 <- step0; slot1 <- raw step1
    loadA(0, 0);
    procStore(0, 0, 0);
    loadA(128, 1);
    __syncthreads();

    // invariant entering step t: buf[t&1] ready; slot[(t+1)&1] holds raw t+1
    for (int t = 0; t < NT; t++) {
        const int k0 = t * 128;
        const int cur = t & 1;
        if (t + 2 < NT)
            loadA(k0 + 256, cur);     // slot cur is free; full step of latency
        #pragma unroll
        for (int kk = 0; kk < 4; kk++) {
            const int kb = kk * 32 + qq * 8;
            u16v8 bf_[4];
            #pragma unroll
            for (int j = 0; j < 4; j++)
                bf_[j] = *(const u16v8*)&Bp[j][k0 + kb];   // L2-resident vT
            u16v8 af_ = *(const u16v8*)&As[cur][m][kb];
            #pragma unroll
            for (int j = 0; j < 4; j++)
                acc[j] = mfma_bf16(af_, bf_[j], acc[j]);
        }
        if (t + 1 < NT) {
            procStore(k0 + 128, (t + 1) & 1, cur ^ 1);
            __syncthreads();
        }
    }

    #pragma unroll
    for (int j = 0; j < 4; j++) {
        #pragma unroll
        for (int r = 0; r < 4; r++) {
            int row = rowBase + qq * 4 + r;
            int col = w * 64 + j * 16 + m;
            __builtin_nontemporal_store(
                acc[j][r], &out[((size_t)b * SS + row) * DD + col]);
        }
    }
}

extern "C" void kernel_launch(void* const* d_in, const int* in_sizes, int n_in,
                              void* d_out, int out_size, void* d_ws, size_t ws_size,
                              hipStream_t stream)
{
    const float* query = (const float*)d_in[0];
    const float* key_  = (const float*)d_in[1];
    const float* value = (const float*)d_in[2];
    const float* Wq    = (const float*)d_in[3];
    const float* Wk    = (const float*)d_in[4];
    const float* Wv    = (const float*)d_in[5];

    float* out  = (float*)d_out;                          // [B,S,D]
    float* attn = out + (size_t)BB * SS * DD;             // [B,S,S]

    const size_t E = (size_t)BB * SS * DD;                // 4.19M elements
    unsigned short* qh = (unsigned short*)d_ws;
    unsigned short* ql = qh + E;
    unsigned short* kh = ql + E;
    unsigned short* kl = kh + E;
    unsigned short* vT = kl + E;
    float* tmaxg  = (float*)(vT + E);                     // [32][16384]
    float* tsumg  = tmaxg + 32 * (size_t)NROWS;           // [32][16384]
    float* rowm   = tsumg + 32 * (size_t)NROWS;           // [16384]
    float* rowinv = rowm + NROWS;                         // [16384]
    unsigned* gmax = (unsigned*)(rowinv + NROWS);

    // 1) projections via split-bf16 MFMA; gmax init
    proj_kernel<<<dim3(DD / 128, (BB * SS) / 128, 3), 256, 0, stream>>>(
        query, key_, value, Wq, Wk, Wv, qh, ql, kh, kl, vT, gmax);
    // 2) raw scores via split-bf16 MFMA + per-row tile stats + global max
    scores_mfma<<<dim3(SS / 128, SS / 128, BB), 256, 0, stream>>>(
        qh, ql, kh, kl, attn, gmax, tmaxg, tsumg);
    // 3) merge tile stats -> per-row (max, 1/sum) with diag bias
    stats_merge<<<dim3(NROWS / 256), 256, 0, stream>>>(
        tmaxg, tsumg, attn, gmax, rowm, rowinv);
    // 4) fused softmax-normalize (writes fp32 attn output) + attn @ v
    av_softmax_mfma<<<dim3(1024), 256, 0, stream>>>(
        attn, vT, rowm, rowinv, gmax, out);
}

// Round 7
// 655.973 us; speedup vs baseline: 1.3132x; 1.1732x over previous
//
#include <hip/hip_runtime.h>
#include <cstdint>
#include <cstddef>

// Problem constants
#define BB 4
#define SS 4096
#define DD 256
#define SCORE_SCALE (1.0f/16.0f)   // 1/sqrt(256)
#define PIW 0.5f
#define NROWS (BB * SS)            // 16384 flattened rows

typedef float          f32x4  __attribute__((ext_vector_type(4)));
typedef __bf16         bf16v8 __attribute__((ext_vector_type(8)));
typedef unsigned short u16v8  __attribute__((ext_vector_type(8)));
typedef unsigned short u16v4  __attribute__((ext_vector_type(4)));

__device__ __forceinline__ f32x4 mfma_bf16(u16v8 a, u16v8 b, f32x4 c) {
    return __builtin_amdgcn_mfma_f32_16x16x32_bf16(
        __builtin_bit_cast(bf16v8, a), __builtin_bit_cast(bf16v8, b), c, 0, 0, 0);
}

__device__ __forceinline__ unsigned short f2bf(float f) {
    unsigned u = __float_as_uint(f);
    u += 0x7FFFu + ((u >> 16) & 1u);           // RNE (inputs finite)
    return (unsigned short)(u >> 16);
}
__device__ __forceinline__ float bf2f(unsigned short h) {
    return __uint_as_float(((unsigned)h) << 16);
}
__device__ __forceinline__ unsigned fenc(float x) {
    unsigned u = __float_as_uint(x);
    return (u & 0x80000000u) ? ~u : (u | 0x80000000u);
}
__device__ __forceinline__ float fdec(unsigned e) {
    return __uint_as_float((e & 0x80000000u) ? (e ^ 0x80000000u) : ~e);
}

// ---------------------------------------------------------------------------
// Projections via split-bf16 MFMA (Ah*Wh + Ah*Wl + Al*Wh ~ fp32 precision):
// C = A[16384,256] @ W[256,256]. 128x128 tile, 4 waves (2x2 of 64x64), BK=32.
// z=0: qh/ql bf16 split. z=1: kh/kl split. z=2: vT bf16 transposed [B][D][S].
// Also inits gmax.
// ---------------------------------------------------------------------------
#define PSPAD 42   // 32 + 10 u16 row stride (W-transpose staging conflicts)

__global__ __launch_bounds__(256) void proj_kernel(
    const float* __restrict__ query, const float* __restrict__ key_, const float* __restrict__ value,
    const float* __restrict__ Wq, const float* __restrict__ Wk, const float* __restrict__ Wv,
    unsigned short* __restrict__ qh, unsigned short* __restrict__ ql,
    unsigned short* __restrict__ kh, unsigned short* __restrict__ kl,
    unsigned short* __restrict__ vT, unsigned* __restrict__ gmax)
{
    const int z = blockIdx.z;
    const float* A = (z == 0) ? query : (z == 1) ? key_ : value;
    const float* W = (z == 0) ? Wq    : (z == 1) ? Wk   : Wv;
    if (z == 0 && blockIdx.x == 0 && blockIdx.y == 0 && threadIdx.x == 0)
        *gmax = 0x007FFFFFu;   // fenc(-inf)

    __shared__ unsigned short Ah[128][PSPAD];
    __shared__ unsigned short Al[128][PSPAD];
    __shared__ unsigned short Bh[128][PSPAD];   // W^T split: [n][k]
    __shared__ unsigned short Bl[128][PSPAD];

    const int tid = threadIdx.x;
    const int lane = tid & 63, w = tid >> 6;
    const int wr = (w >> 1) * 64, wc = (w & 1) * 64;
    const int m = lane & 15, qq = lane >> 4;
    const int rowBase = blockIdx.y * 128;   // flattened B*S row
    const int colBase = blockIdx.x * 128;

    f32x4 acc[4][4];
    #pragma unroll
    for (int i = 0; i < 4; i++)
        #pragma unroll
        for (int j = 0; j < 4; j++)
            acc[i][j] = (f32x4){0.f, 0.f, 0.f, 0.f};

    const int chunk = (tid & 3) * 8;   // float offset within 32-wide k-slab
    const int srow  = tid >> 2;        // 0..63

    for (int k0 = 0; k0 < DD; k0 += 32) {
        // A staging: rows srow, srow+64; 8 fp32 -> bf16 h/l
        #pragma unroll
        for (int i = 0; i < 2; i++) {
            int r = srow + i * 64;
            const float* src = &A[(size_t)(rowBase + r) * DD + k0 + chunk];
            float4 f0 = *(const float4*)src;
            float4 f1 = *(const float4*)(src + 4);
            float v[8] = {f0.x, f0.y, f0.z, f0.w, f1.x, f1.y, f1.z, f1.w};
            u16v8 h, l;
            #pragma unroll
            for (int e = 0; e < 8; e++) {
                h[e] = f2bf(v[e]);
                l[e] = f2bf(v[e] - bf2f(h[e]));
            }
            *(u16v8*)&Ah[r][chunk] = h;
            *(u16v8*)&Al[r][chunk] = l;
        }
        // W staging transposed: W[k0+kk][colBase+n] -> Bh/Bl[n][kk]
        #pragma unroll
        for (int i = 0; i < 4; i++) {
            int idx = tid + i * 256;
            int kk = idx >> 5, nq = idx & 31;
            float4 f = *(const float4*)&W[(size_t)(k0 + kk) * DD + colBase + nq * 4];
            float v[4] = {f.x, f.y, f.z, f.w};
            #pragma unroll
            for (int e = 0; e < 4; e++) {
                unsigned short h = f2bf(v[e]);
                unsigned short l = f2bf(v[e] - bf2f(h));
                Bh[nq * 4 + e][kk] = h;
                Bl[nq * 4 + e][kk] = l;
            }
        }
        __syncthreads();

        const int kb = qq * 8;
        u16v8 ah[4], al[4], bh[4], bl[4];
        #pragma unroll
        for (int i = 0; i < 4; i++) {
            ah[i] = *(const u16v8*)&Ah[wr + i * 16 + m][kb];
            al[i] = *(const u16v8*)&Al[wr + i * 16 + m][kb];
            bh[i] = *(const u16v8*)&Bh[wc + i * 16 + m][kb];
            bl[i] = *(const u16v8*)&Bl[wc + i * 16 + m][kb];
        }
        #pragma unroll
        for (int i = 0; i < 4; i++)
            #pragma unroll
            for (int j = 0; j < 4; j++) {
                acc[i][j] = mfma_bf16(ah[i], bh[j], acc[i][j]);
                acc[i][j] = mfma_bf16(ah[i], bl[j], acc[i][j]);
                acc[i][j] = mfma_bf16(al[i], bh[j], acc[i][j]);
            }
        __syncthreads();
    }

    // epilogue: lane (m,qq) holds C[rowBase+wr+i*16+qq*4+r][colBase+wc+j*16+m]
    #pragma unroll
    for (int i = 0; i < 4; i++) {
        #pragma unroll
        for (int j = 0; j < 4; j++) {
            #pragma unroll
            for (int r = 0; r < 4; r++) {
                const int gr  = rowBase + wr + i * 16 + qq * 4 + r;
                const int col = colBase + wc + j * 16 + m;
                const float v = acc[i][j][r];
                if (z == 2) {
                    const int b2 = gr >> 12, s2 = gr & (SS - 1);
                    vT[((size_t)b2 * DD + col) * SS + s2] = f2bf(v);
                } else {
                    unsigned short h = f2bf(v);
                    unsigned short l = f2bf(v - bf2f(h));
                    unsigned short* H = (z == 0) ? qh : kh;
                    unsigned short* L = (z == 0) ? ql : kl;
                    H[(size_t)gr * DD + col] = h;
                    L[(size_t)gr * DD + col] = l;
                }
            }
        }
    }
}

// ---------------------------------------------------------------------------
// Scores: C = (q@k^T)/16 via split-bf16 MFMA: qh*kh + qh*kl + ql*kh.
// 128x128 C-tile, 4 waves (2x2 of 64x64), BK=32.
// Epilogue: per-row (max, sumexp) over this 128-col tile -> tmaxg/tsumg,
// plus block max -> gmax. All computed from register-resident acc.
// ---------------------------------------------------------------------------
#define SPAD 40   // 32 + 8 bf16 LDS row stride

__global__ __launch_bounds__(256) void scores_mfma(
    const unsigned short* __restrict__ qh, const unsigned short* __restrict__ ql,
    const unsigned short* __restrict__ kh, const unsigned short* __restrict__ kl,
    float* __restrict__ attn, unsigned* __restrict__ gmax,
    float* __restrict__ tmaxg, float* __restrict__ tsumg)
{
    const int b = blockIdx.z;
    const size_t boff = (size_t)b * SS * DD;
    const unsigned short* Qh = qh + boff;
    const unsigned short* Ql = ql + boff;
    const unsigned short* Kh = kh + boff;
    const unsigned short* Kl = kl + boff;
    float* C = attn + (size_t)b * SS * SS;

    __shared__ unsigned short Ah[128][SPAD];
    __shared__ unsigned short Al[128][SPAD];
    __shared__ unsigned short Bh[128][SPAD];
    __shared__ unsigned short Bl[128][SPAD];
    __shared__ float s_m[4][64];
    __shared__ float s_s[4][64];
    __shared__ float red[128];

    const int tid = threadIdx.x;
    const int lane = tid & 63, w = tid >> 6;
    const int wr = (w >> 1) * 64, wc = (w & 1) * 64;
    const int m = lane & 15, qq = lane >> 4;
    const int rowBase = blockIdx.y * 128;
    const int colBase = blockIdx.x * 128;

    f32x4 acc[4][4];
    #pragma unroll
    for (int i = 0; i < 4; i++)
        #pragma unroll
        for (int j = 0; j < 4; j++)
            acc[i][j] = (f32x4){0.f, 0.f, 0.f, 0.f};

    const int chunk = (tid & 3) * 8;        // bf16 offset within 32-wide k-slab
    const int srow  = tid >> 2;             // 0..63

    for (int k0 = 0; k0 < DD; k0 += 32) {
        #pragma unroll
        for (int i = 0; i < 2; i++) {
            int r = srow + i * 64;
            size_t ga = (size_t)(rowBase + r) * DD + k0 + chunk;
            size_t gb = (size_t)(colBase + r) * DD + k0 + chunk;
            *(u16v8*)&Ah[r][chunk] = *(const u16v8*)&Qh[ga];
            *(u16v8*)&Al[r][chunk] = *(const u16v8*)&Ql[ga];
            *(u16v8*)&Bh[r][chunk] = *(const u16v8*)&Kh[gb];
            *(u16v8*)&Bl[r][chunk] = *(const u16v8*)&Kl[gb];
        }
        __syncthreads();

        const int kb = qq * 8;
        u16v8 ah[4], al[4], bh[4], bl[4];
        #pragma unroll
        for (int i = 0; i < 4; i++) {
            ah[i] = *(const u16v8*)&Ah[wr + i * 16 + m][kb];
            al[i] = *(const u16v8*)&Al[wr + i * 16 + m][kb];
            bh[i] = *(const u16v8*)&Bh[wc + i * 16 + m][kb];
            bl[i] = *(const u16v8*)&Bl[wc + i * 16 + m][kb];
        }
        #pragma unroll
        for (int i = 0; i < 4; i++)
            #pragma unroll
            for (int j = 0; j < 4; j++) {
                acc[i][j] = mfma_bf16(ah[i], bh[j], acc[i][j]);
                acc[i][j] = mfma_bf16(ah[i], bl[j], acc[i][j]);
                acc[i][j] = mfma_bf16(al[i], bh[j], acc[i][j]);
            }
        __syncthreads();
    }

    // scale once; all consumers (C store, stats, gmax) use scaled values
    #pragma unroll
    for (int i = 0; i < 4; i++)
        #pragma unroll
        for (int j = 0; j < 4; j++)
            acc[i][j] *= SCORE_SCALE;

    // store raw scores (nontemporal: pure stream)
    #pragma unroll
    for (int i = 0; i < 4; i++)
        #pragma unroll
        for (int j = 0; j < 4; j++)
            #pragma unroll
            for (int r = 0; r < 4; r++) {
                int row = rowBase + wr + i * 16 + qq * 4 + r;
                int col = colBase + wc + j * 16 + m;
                __builtin_nontemporal_store(acc[i][j][r], &C[(size_t)row * SS + col]);
            }

    // ---- per-row tile stats (flash-style), register resident ----
    float lmax[16];
    #pragma unroll
    for (int i = 0; i < 4; i++)
        #pragma unroll
        for (int r = 0; r < 4; r++)
            lmax[i * 4 + r] = fmaxf(fmaxf(acc[i][0][r], acc[i][1][r]),
                                    fmaxf(acc[i][2][r], acc[i][3][r]));
    #pragma unroll
    for (int t = 0; t < 16; t++) {
        #pragma unroll
        for (int msk = 1; msk < 16; msk <<= 1)
            lmax[t] = fmaxf(lmax[t], __shfl_xor(lmax[t], msk));
    }
    if (m == 0) {
        #pragma unroll
        for (int i = 0; i < 4; i++)
            #pragma unroll
            for (int r = 0; r < 4; r++)
                s_m[w][i * 16 + qq * 4 + r] = lmax[i * 4 + r];
    }
    __syncthreads();
    float lsum[16];
    #pragma unroll
    for (int i = 0; i < 4; i++)
        #pragma unroll
        for (int r = 0; r < 4; r++) {
            int idx = i * 16 + qq * 4 + r;
            float rm = fmaxf(s_m[w][idx], s_m[w ^ 1][idx]);
            float s = 0.f;
            #pragma unroll
            for (int j = 0; j < 4; j++)
                s += __expf(acc[i][j][r] - rm);
            lsum[i * 4 + r] = s;
        }
    #pragma unroll
    for (int t = 0; t < 16; t++) {
        #pragma unroll
        for (int msk = 1; msk < 16; msk <<= 1)
            lsum[t] += __shfl_xor(lsum[t], msk);
    }
    if (m == 0) {
        #pragma unroll
        for (int i = 0; i < 4; i++)
            #pragma unroll
            for (int r = 0; r < 4; r++)
                s_s[w][i * 16 + qq * 4 + r] = lsum[i * 4 + r];
    }
    __syncthreads();

    if (tid < 128) {
        int wp = tid >> 6, lr = tid & 63;
        float tm = fmaxf(s_m[2 * wp][lr], s_m[2 * wp + 1][lr]);
        float ts = s_s[2 * wp][lr] + s_s[2 * wp + 1][lr];   // same reference max
        size_t gi = (size_t)blockIdx.x * NROWS + (size_t)b * SS + rowBase + tid;
        tmaxg[gi] = tm;
        tsumg[gi] = ts;
        red[tid] = tm;
    }
    __syncthreads();
    for (int s2 = 64; s2 > 0; s2 >>= 1) {
        if (tid < s2) red[tid] = fmaxf(red[tid], red[tid + s2]);
        __syncthreads();
    }
    if (tid == 0) atomicMax(gmax, fenc(red[0]));
}

// ---------------------------------------------------------------------------
// Merge per-tile stats into per-row (max, 1/sum), folding in the diag bias
// (needs final gmax). Reads 4 MB stats + 16K diag elements. Tiny.
// ---------------------------------------------------------------------------
__global__ __launch_bounds__(256) void stats_merge(
    const float* __restrict__ tmaxg, const float* __restrict__ tsumg,
    const float* __restrict__ attn, const unsigned* __restrict__ gmax,
    float* __restrict__ rowm, float* __restrict__ rowinv)
{
    const int grow = blockIdx.x * 256 + threadIdx.x;   // 0..16383
    const int b = grow >> 12, i = grow & (SS - 1);
    const float bias = PIW * fdec(*gmax);

    float tm[32];
    float mx = -INFINITY;
    #pragma unroll
    for (int t = 0; t < 32; t++) {
        tm[t] = tmaxg[(size_t)t * NROWS + grow];
        mx = fmaxf(mx, tm[t]);
    }
    const float dii = attn[(size_t)b * SS * SS + (size_t)i * SS + i];
    mx = fmaxf(mx, dii + bias);

    float s = 0.f;
    #pragma unroll
    for (int t = 0; t < 32; t++)
        s += tsumg[(size_t)t * NROWS + grow] * __expf(tm[t] - mx);
    // replace unbiased diag contribution with biased one
    s += __expf(dii + bias - mx) - __expf(dii - mx);

    rowm[grow] = mx;
    rowinv[grow] = 1.0f / s;
}

// ---------------------------------------------------------------------------
// Fused softmax + AV. BM=32, BN=256, BK=256 (16 fat steps). Grid 512
// (XCD-aware decode: batch pinned to an XCD pair -> vT L2-resident).
// Per step each thread streams 8 f32x4 of raw scores (128 B in flight,
// 32 KB/block, 64 KB/CU), exps once (diag bias folded), writes fp32 weights
// back (nt), stages bf16 into a double-buffered LDS tile. B fragments read
// per-lane from L2. One __syncthreads per 256-wide K step.
// ---------------------------------------------------------------------------
#define AVBK 256

__global__ __launch_bounds__(256) void av_softmax_mfma(
    float* __restrict__ attn, const unsigned short* __restrict__ vT,
    const float* __restrict__ rowm, const float* __restrict__ rowinv,
    const unsigned* __restrict__ gmax, float* __restrict__ out)
{
    // block i -> XCD i%8; batch b owns XCDs {2b, 2b+1}
    const int lin = blockIdx.x;
    const int b = (lin & 7) >> 1;
    const int rowTile = ((lin >> 3) << 1) | (lin & 1);   // 0..127
    const int rowBase = rowTile * 32;

    float* A = attn + (size_t)b * SS * SS;
    const unsigned short* Bv = vT + (size_t)b * DD * SS;   // [256][4096]
    const float bias = PIW * fdec(*gmax);

    __shared__ unsigned short As[2][32][264];   // bf16 A tile, dbuf, +8 pad

    const int tid = threadIdx.x;
    const int lane = tid & 63, w = tid >> 6;
    const int m = lane & 15, qq = lane >> 4;

    // A-staging map: thread owns row ra, fp32 cols c8*4 + u*32 (u=0..7)
    const int ra = tid >> 3;              // 0..31
    const int c8 = tid & 7;               // 0..7
    const int rr = rowBase + ra;
    float* Arow = A + (size_t)rr * SS;
    const float mr = rowm[b * SS + rr];
    const float ri = rowinv[b * SS + rr];

    // per-lane vT row bases (constant over k)
    const unsigned short* Bp[4];
    #pragma unroll
    for (int j = 0; j < 4; j++)
        Bp[j] = Bv + (size_t)(w * 64 + j * 16 + m) * SS;

    f32x4 acc[2][4];
    #pragma unroll
    for (int i = 0; i < 2; i++)
        #pragma unroll
        for (int j = 0; j < 4; j++)
            acc[i][j] = (f32x4){0.f, 0.f, 0.f, 0.f};

    f32x4 pf[8];   // 8 float4 per thread in flight per step

    auto loadA = [&](int kbase) {
        #pragma unroll
        for (int u = 0; u < 8; u++)
            pf[u] = *(const f32x4*)&Arow[kbase + c8 * 4 + u * 32];
    };
    // exp-normalize pf, write fp32 weights back (nt), stage bf16 -> As[buf]
    auto procStore = [&](int kbase, int buf) {
        #pragma unroll
        for (int u = 0; u < 8; u++) {
            int c = c8 * 4 + u * 32;
            int j0 = kbase + c;
            float e0 = pf[u][0] + ((j0 + 0 == rr) ? bias : 0.0f);
            float e1 = pf[u][1] + ((j0 + 1 == rr) ? bias : 0.0f);
            float e2 = pf[u][2] + ((j0 + 2 == rr) ? bias : 0.0f);
            float e3 = pf[u][3] + ((j0 + 3 == rr) ? bias : 0.0f);
            float w0 = __expf(e0 - mr) * ri;
            float w1 = __expf(e1 - mr) * ri;
            float w2 = __expf(e2 - mr) * ri;
            float w3 = __expf(e3 - mr) * ri;
            f32x4 wv = (f32x4){w0, w1, w2, w3};
            __builtin_nontemporal_store(wv, (f32x4*)&Arow[j0]);
            *(u16v4*)&As[buf][ra][c] =
                (u16v4){f2bf(w0), f2bf(w1), f2bf(w2), f2bf(w3)};
        }
    };

    const int NT = SS / AVBK;   // 16 K-steps

    loadA(0);
    procStore(0, 0);
    __syncthreads();

    for (int t = 0; t < NT; t++) {
        const int k0 = t * AVBK;
        const int cur = t & 1;
        if (t + 1 < NT)
            loadA(k0 + AVBK);           // 8 loads in flight across MFMA phase
        #pragma unroll
        for (int kk = 0; kk < 8; kk++) {
            const int kb = kk * 32 + qq * 8;
            u16v8 bf_[4], af_[2];
            #pragma unroll
            for (int j = 0; j < 4; j++)
                bf_[j] = *(const u16v8*)&Bp[j][k0 + kb];   // L2-resident vT
            #pragma unroll
            for (int i = 0; i < 2; i++)
                af_[i] = *(const u16v8*)&As[cur][i * 16 + m][kb];
            #pragma unroll
            for (int i = 0; i < 2; i++)
                #pragma unroll
                for (int j = 0; j < 4; j++)
                    acc[i][j] = mfma_bf16(af_[i], bf_[j], acc[i][j]);
        }
        if (t + 1 < NT) {
            procStore(k0 + AVBK, cur ^ 1);
            __syncthreads();
        }
    }

    #pragma unroll
    for (int i = 0; i < 2; i++) {
        #pragma unroll
        for (int j = 0; j < 4; j++) {
            #pragma unroll
            for (int r = 0; r < 4; r++) {
                int row = rowBase + i * 16 + qq * 4 + r;
                int col = w * 64 + j * 16 + m;
                __builtin_nontemporal_store(
                    acc[i][j][r], &out[((size_t)b * SS + row) * DD + col]);
            }
        }
    }
}

extern "C" void kernel_launch(void* const* d_in, const int* in_sizes, int n_in,
                              void* d_out, int out_size, void* d_ws, size_t ws_size,
                              hipStream_t stream)
{
    const float* query = (const float*)d_in[0];
    const float* key_  = (const float*)d_in[1];
    const float* value = (const float*)d_in[2];
    const float* Wq    = (const float*)d_in[3];
    const float* Wk    = (const float*)d_in[4];
    const float* Wv    = (const float*)d_in[5];

    float* out  = (float*)d_out;                          // [B,S,D]
    float* attn = out + (size_t)BB * SS * DD;             // [B,S,S]

    const size_t E = (size_t)BB * SS * DD;                // 4.19M elements
    unsigned short* qh = (unsigned short*)d_ws;
    unsigned short* ql = qh + E;
    unsigned short* kh = ql + E;
    unsigned short* kl = kh + E;
    unsigned short* vT = kl + E;
    float* tmaxg  = (float*)(vT + E);                     // [32][16384]
    float* tsumg  = tmaxg + 32 * (size_t)NROWS;           // [32][16384]
    float* rowm   = tsumg + 32 * (size_t)NROWS;           // [16384]
    float* rowinv = rowm + NROWS;                         // [16384]
    unsigned* gmax = (unsigned*)(rowinv + NROWS);

    // 1) projections via split-bf16 MFMA; gmax init
    proj_kernel<<<dim3(DD / 128, (BB * SS) / 128, 3), 256, 0, stream>>>(
        query, key_, value, Wq, Wk, Wv, qh, ql, kh, kl, vT, gmax);
    // 2) raw scores via split-bf16 MFMA + per-row tile stats + global max
    scores_mfma<<<dim3(SS / 128, SS / 128, BB), 256, 0, stream>>>(
        qh, ql, kh, kl, attn, gmax, tmaxg, tsumg);
    // 3) merge tile stats -> per-row (max, 1/sum) with diag bias
    stats_merge<<<dim3(NROWS / 256), 256, 0, stream>>>(
        tmaxg, tsumg, attn, gmax, rowm, rowinv);
    // 4) fused softmax-normalize (writes fp32 attn output) + attn @ v
    av_softmax_mfma<<<dim3(512), 256, 0, stream>>>(
        attn, vT, rowm, rowinv, gmax, out);
}